// Round 8
// baseline (210.964 us; speedup 1.0000x reference)
//
#include <hip/hip_runtime.h>

#define N_NODES 50000
#define N_EDGES 800000
#define D 64
#define NSLICE 8
#define SLICE_N ((N_NODES + NSLICE - 1) / NSLICE)   // 6250
#define BCAP 64        // bucket capacity; deg ~ Poisson(16), P(deg>=64) ~ 1e-19

// float -> bf16 (round-to-nearest-even), as raw ushort
__device__ __forceinline__ unsigned short f2bf(float f) {
    unsigned int u = __builtin_bit_cast(unsigned int, f);
    u += 0x7fffu + ((u >> 16) & 1u);
    return (unsigned short)(u >> 16);
}
// unpack a uint holding two bf16 (little-endian: low ushort = even feature)
__device__ __forceinline__ float bflo(unsigned int u) {
    return __builtin_bit_cast(float, u << 16);
}
__device__ __forceinline__ float bfhi(unsigned int u) {
    return __builtin_bit_cast(float, u & 0xffff0000u);
}

// ---------------- bucketed CSR fill (XCD-partitioned by dst slice) ----------------
__global__ __launch_bounds__(256) void k_fill2(const int* __restrict__ src,
                                               const int* __restrict__ dst,
                                               int* __restrict__ cnt,
                                               int* __restrict__ csr) {
    int slice = blockIdx.x & (NSLICE - 1);
    int lo = slice * SLICE_N, hi = lo + SLICE_N;
    int gblk = blockIdx.x >> 3, nblk = gridDim.x >> 3;
    for (int e = gblk * blockDim.x + threadIdx.x; e < N_EDGES; e += nblk * blockDim.x) {
        int d = dst[e];
        if (d >= lo && d < hi) {
            int p = atomicAdd(&cnt[d], 1);
            csr[(d << 6) + p] = src[e];
        }
    }
}

// ---------------- transform: yS = h@Ws + b (fp32), yN split bf16 halves ----------------
// Identical math to R7; only the yN store targets changed: features 0-31 ->
// yNa (64 B rows), 32-63 -> yNb. Each 3.2 MB array fits a single XCD L2.
__global__ __launch_bounds__(256, 4) void k_xform(const float* __restrict__ h,
        const float* __restrict__ Ws, const float* __restrict__ Wn,
        const float* __restrict__ b,
        float* __restrict__ yS,
        unsigned short* __restrict__ yNa, unsigned short* __restrict__ yNb) {
    int lane = threadIdx.x & 63;
    int gwave = __builtin_amdgcn_readfirstlane((blockIdx.x * blockDim.x + threadIdx.x) >> 6);
    int nwaves = (gridDim.x * blockDim.x) >> 6;

    int mat = gwave & 1;
    const float* W = mat ? Wn : Ws;

    float w[D];
#pragma unroll
    for (int k = 0; k < D; ++k) w[k] = W[k * D + lane];
    float bj = mat ? 0.f : b[lane];

    unsigned short* yH = (lane < 32) ? yNa : yNb;
    int fl = lane & 31;

    const int ngroups = (N_NODES + 3) / 4;   // 12500, exact
    for (int g = gwave >> 1; g < ngroups; g += (nwaves >> 1)) {
        const float* x0 = h + (size_t)(g * 4) * D;
        float a0 = bj, a1 = bj, a2 = bj, a3 = bj;
#pragma unroll
        for (int kq = 0; kq < 16; ++kq) {
            float4 v0 = *(const float4*)(x0 + 0 * D + kq * 4);
            float4 v1 = *(const float4*)(x0 + 1 * D + kq * 4);
            float4 v2 = *(const float4*)(x0 + 2 * D + kq * 4);
            float4 v3 = *(const float4*)(x0 + 3 * D + kq * 4);
            a0 = fmaf(v0.x, w[kq * 4 + 0], a0);
            a1 = fmaf(v1.x, w[kq * 4 + 0], a1);
            a2 = fmaf(v2.x, w[kq * 4 + 0], a2);
            a3 = fmaf(v3.x, w[kq * 4 + 0], a3);
            a0 = fmaf(v0.y, w[kq * 4 + 1], a0);
            a1 = fmaf(v1.y, w[kq * 4 + 1], a1);
            a2 = fmaf(v2.y, w[kq * 4 + 1], a2);
            a3 = fmaf(v3.y, w[kq * 4 + 1], a3);
            a0 = fmaf(v0.z, w[kq * 4 + 2], a0);
            a1 = fmaf(v1.z, w[kq * 4 + 2], a1);
            a2 = fmaf(v2.z, w[kq * 4 + 2], a2);
            a3 = fmaf(v3.z, w[kq * 4 + 2], a3);
            a0 = fmaf(v0.w, w[kq * 4 + 3], a0);
            a1 = fmaf(v1.w, w[kq * 4 + 3], a1);
            a2 = fmaf(v2.w, w[kq * 4 + 3], a2);
            a3 = fmaf(v3.w, w[kq * 4 + 3], a3);
        }
        int row = g * 4;
        if (mat) {
            yH[(row + 0) * 32 + fl] = f2bf(a0);
            yH[(row + 1) * 32 + fl] = f2bf(a1);
            yH[(row + 2) * 32 + fl] = f2bf(a2);
            yH[(row + 3) * 32 + fl] = f2bf(a3);
        } else {
            size_t base = (size_t)row * D + lane;
            yS[base + 0 * D] = a0;
            yS[base + 1 * D] = a1;
            yS[base + 2 * D] = a2;
            yS[base + 3 * D] = a3;
        }
    }
}

// ---------------- split mean-aggregate + self + epilogue ----------------
// Half-feature gather: rows are 64 B (32 bf16 = 8 uint2). Block's XCD slot
// (blockIdx&7) picks the half: xcd 0-3 -> yNa, 4-7 -> yNb, so each XCD's L2
// holds one 3.2 MB array (fits 4 MiB) -> gather becomes L2-hit instead of
// MSHR-bound LLC misses. q=lane>>3 picks 1 of 8 edges per gather instr,
// fq=lane&7 picks the uint2. One unconditional 32-edge round (masked slots
// read row 0, contribute *0.0f exactly); deg>32 is ~3e-5.
__global__ __launch_bounds__(256) void k_aggf2(const char* __restrict__ yA,
        const char* __restrict__ yB,
        const float* __restrict__ yS,
        const int* __restrict__ cnt, const int* __restrict__ csr,
        float* __restrict__ out, int relu) {
    int xcd  = blockIdx.x & 7;
    int half = xcd >> 2;
    int g    = (blockIdx.x >> 3) * 4 + (xcd & 3);          // [0, 12500)
    int node = __builtin_amdgcn_readfirstlane((g << 2) + (int)(threadIdx.x >> 6)); // [0, 50000)
    const char* yH = half ? yB : yA;
    int ho = half << 5;
    int lane = threadIdx.x & 63;
    int q  = lane >> 3;            // edge sub-slot 0..7
    int fq = lane & 7;             // uint2 slot within the 64 B row
    int deg = cnt[node];
    const int* bucket = csr + (node << 6);
    unsigned foff = (unsigned)fq * 8u;

    float s0 = 0.f, s1 = 0.f, s2 = 0.f, s3 = 0.f;

#define ROUND32(E0)                                                         \
    {                                                                       \
        int i0 = (E0) + q, i1 = i0 + 8, i2 = i0 + 16, i3 = i0 + 24;         \
        int b0 = bucket[i0], b1 = bucket[i1], b2 = bucket[i2], b3 = bucket[i3]; \
        unsigned a0 = (i0 < deg) ? ((unsigned)b0 << 6) : 0u;                \
        unsigned a1 = (i1 < deg) ? ((unsigned)b1 << 6) : 0u;                \
        unsigned a2 = (i2 < deg) ? ((unsigned)b2 << 6) : 0u;                \
        unsigned a3 = (i3 < deg) ? ((unsigned)b3 << 6) : 0u;                \
        float m0 = (i0 < deg) ? 1.f : 0.f;                                  \
        float m1 = (i1 < deg) ? 1.f : 0.f;                                  \
        float m2 = (i2 < deg) ? 1.f : 0.f;                                  \
        float m3 = (i3 < deg) ? 1.f : 0.f;                                  \
        uint2 u0 = *(const uint2*)(yH + a0 + foff);                         \
        uint2 u1 = *(const uint2*)(yH + a1 + foff);                         \
        uint2 u2 = *(const uint2*)(yH + a2 + foff);                         \
        uint2 u3 = *(const uint2*)(yH + a3 + foff);                         \
        s0 = fmaf(m0, bflo(u0.x), s0); s0 = fmaf(m1, bflo(u1.x), s0);       \
        s0 = fmaf(m2, bflo(u2.x), s0); s0 = fmaf(m3, bflo(u3.x), s0);       \
        s1 = fmaf(m0, bfhi(u0.x), s1); s1 = fmaf(m1, bfhi(u1.x), s1);       \
        s1 = fmaf(m2, bfhi(u2.x), s1); s1 = fmaf(m3, bfhi(u3.x), s1);       \
        s2 = fmaf(m0, bflo(u0.y), s2); s2 = fmaf(m1, bflo(u1.y), s2);       \
        s2 = fmaf(m2, bflo(u2.y), s2); s2 = fmaf(m3, bflo(u3.y), s2);       \
        s3 = fmaf(m0, bfhi(u0.y), s3); s3 = fmaf(m1, bfhi(u1.y), s3);       \
        s3 = fmaf(m2, bfhi(u2.y), s3); s3 = fmaf(m3, bfhi(u3.y), s3);       \
    }

    ROUND32(0)
    if (deg > 32) ROUND32(32)      // scalar branch, ~3e-5 of waves
#undef ROUND32

    // merge the 8 edge-slots (xor over the three q bits: 8, 16, 32)
    s0 += __shfl_xor(s0, 8, 64); s0 += __shfl_xor(s0, 16, 64); s0 += __shfl_xor(s0, 32, 64);
    s1 += __shfl_xor(s1, 8, 64); s1 += __shfl_xor(s1, 16, 64); s1 += __shfl_xor(s1, 32, 64);
    s2 += __shfl_xor(s2, 8, 64); s2 += __shfl_xor(s2, 16, 64); s2 += __shfl_xor(s2, 32, 64);
    s3 += __shfl_xor(s3, 8, 64); s3 += __shfl_xor(s3, 16, 64); s3 += __shfl_xor(s3, 32, 64);

    if (q < 4) {                   // 32 writer lanes cover this half's 32 features
        int f = ho + fq * 4 + q;
        float self = yS[(size_t)node * D + f];
        float inv = 1.0f / fmaxf((float)deg, 1.0f);
        float sv = (q == 0) ? s0 : (q == 1) ? s1 : (q == 2) ? s2 : s3;
        float acc = self + sv * inv;
        if (relu) acc = fmaxf(acc, 0.f);
        out[(size_t)node * D + f] = acc;
    }
}

extern "C" void kernel_launch(void* const* d_in, const int* in_sizes, int n_in,
                              void* d_out, int out_size, void* d_ws, size_t ws_size,
                              hipStream_t stream) {
    const float* x   = (const float*)d_in[0];
    const int*   src = (const int*)d_in[1];
    const int*   dst = (const int*)d_in[2];
    const float* Ws0 = (const float*)d_in[3];
    const float* Wn0 = (const float*)d_in[4];
    const float* b0  = (const float*)d_in[5];
    const float* Ws1 = (const float*)d_in[6];
    const float* Wn1 = (const float*)d_in[7];
    const float* b1  = (const float*)d_in[8];
    float* out = (float*)d_out;

    // workspace layout
    char* p = (char*)d_ws;
    float*          yS  = (float*)p;          p += (size_t)N_NODES * D * sizeof(float);
    unsigned short* yNa = (unsigned short*)p; p += (size_t)N_NODES * 32 * sizeof(unsigned short);
    unsigned short* yNb = (unsigned short*)p; p += (size_t)N_NODES * 32 * sizeof(unsigned short);
    int* cnt = (int*)p;                       p += (size_t)N_NODES * sizeof(int);
    int* csr = (int*)p;                       p += (size_t)N_NODES * BCAP * sizeof(int);

    // zero the bucket cursors
    hipMemsetAsync(cnt, 0, (size_t)N_NODES * sizeof(int), stream);

    // build bucketed CSR (dst-grouped src lists); cnt becomes the degree
    k_fill2<<<1024, 256, 0, stream>>>(src, dst, cnt, csr);

    const int aggBlocks = 25000;   // 2 halves x 12500 node-blocks (4 waves each)

    // layer 0
    k_xform<<<1024, 256, 0, stream>>>(x, Ws0, Wn0, b0, yS, yNa, yNb);
    k_aggf2<<<aggBlocks, 256, 0, stream>>>((const char*)yNa, (const char*)yNb,
                                           yS, cnt, csr, out, 1);
    // layer 1
    k_xform<<<1024, 256, 0, stream>>>(out, Ws1, Wn1, b1, yS, yNa, yNb);
    k_aggf2<<<aggBlocks, 256, 0, stream>>>((const char*)yNa, (const char*)yNb,
                                           yS, cnt, csr, out, 0);
}

// Round 9
// 199.277 us; speedup vs baseline: 1.0586x; 1.0586x over previous
//
#include <hip/hip_runtime.h>

#define N_NODES 50000
#define N_EDGES 800000
#define D 64
#define NSLICE 8
#define SLICE_N ((N_NODES + NSLICE - 1) / NSLICE)   // 6250
#define BCAP 64        // bucket capacity; deg ~ Poisson(16), P(deg>=64) ~ 1e-19

// float -> bf16 (round-to-nearest-even), as raw ushort
__device__ __forceinline__ unsigned short f2bf(float f) {
    unsigned int u = __builtin_bit_cast(unsigned int, f);
    u += 0x7fffu + ((u >> 16) & 1u);
    return (unsigned short)(u >> 16);
}
// unpack a uint holding two bf16 (little-endian: low ushort = even feature)
__device__ __forceinline__ float bflo(unsigned int u) {
    return __builtin_bit_cast(float, u << 16);
}
__device__ __forceinline__ float bfhi(unsigned int u) {
    return __builtin_bit_cast(float, u & 0xffff0000u);
}

// ---------------- bucketed CSR fill (XCD-partitioned by dst slice) ----------------
// Node i owns csr[i*64 .. i*64+63]; cnt[i] is the atomic cursor and doubles as
// the degree. Slice partition (blockIdx&7) keeps each bucket line dirty in one
// XCD's L2 (R2 showed 17x write amplification without it). cnt is zeroed by
// the preceding k_xform dispatch (stream-ordered).
__global__ __launch_bounds__(256) void k_fill2(const int* __restrict__ src,
                                               const int* __restrict__ dst,
                                               int* __restrict__ cnt,
                                               int* __restrict__ csr) {
    int slice = blockIdx.x & (NSLICE - 1);
    int lo = slice * SLICE_N, hi = lo + SLICE_N;
    int gblk = blockIdx.x >> 3, nblk = gridDim.x >> 3;
    for (int e = gblk * blockDim.x + threadIdx.x; e < N_EDGES; e += nblk * blockDim.x) {
        int d = dst[e];
        if (d >= lo && d < hi) {
            int p = atomicAdd(&cnt[d], 1);
            csr[(d << 6) + p] = src[e];
        }
    }
}

// ---------------- transform: yS = h@Ws + b (fp32), yN = h@Wn (bf16) ----------------
// Wave-specialized (even waves -> Ws/yS, odd -> Wn/yN). Lane = output column,
// W column held in 64 VGPRs; h rows read as wave-uniform float4 (scalarizable).
// zero_cnt=1 (layer 0 only): first 196 blocks also zero cnt[] — replaces the
// hipMemsetAsync dispatch (~4-6 us launch overhead each; R5->R6 showed -4
// dispatches = -43 us). Safe: k_fill2 launches after this kernel completes.
__global__ __launch_bounds__(256, 4) void k_xform(const float* __restrict__ h,
        const float* __restrict__ Ws, const float* __restrict__ Wn,
        const float* __restrict__ b,
        float* __restrict__ yS, unsigned short* __restrict__ yN,
        int* __restrict__ cnt, int zero_cnt) {
    if (zero_cnt && blockIdx.x < 196) {
        int i = blockIdx.x * 256 + threadIdx.x;
        if (i < N_NODES) cnt[i] = 0;
    }
    int lane = threadIdx.x & 63;
    int gwave = __builtin_amdgcn_readfirstlane((blockIdx.x * blockDim.x + threadIdx.x) >> 6);
    int nwaves = (gridDim.x * blockDim.x) >> 6;

    int mat = gwave & 1;
    const float* W = mat ? Wn : Ws;

    float w[D];
#pragma unroll
    for (int k = 0; k < D; ++k) w[k] = W[k * D + lane];
    float bj = mat ? 0.f : b[lane];

    const int ngroups = (N_NODES + 3) / 4;   // 12500, exact
    for (int g = gwave >> 1; g < ngroups; g += (nwaves >> 1)) {
        const float* x0 = h + (size_t)(g * 4) * D;
        float a0 = bj, a1 = bj, a2 = bj, a3 = bj;
#pragma unroll
        for (int kq = 0; kq < 16; ++kq) {
            float4 v0 = *(const float4*)(x0 + 0 * D + kq * 4);
            float4 v1 = *(const float4*)(x0 + 1 * D + kq * 4);
            float4 v2 = *(const float4*)(x0 + 2 * D + kq * 4);
            float4 v3 = *(const float4*)(x0 + 3 * D + kq * 4);
            a0 = fmaf(v0.x, w[kq * 4 + 0], a0);
            a1 = fmaf(v1.x, w[kq * 4 + 0], a1);
            a2 = fmaf(v2.x, w[kq * 4 + 0], a2);
            a3 = fmaf(v3.x, w[kq * 4 + 0], a3);
            a0 = fmaf(v0.y, w[kq * 4 + 1], a0);
            a1 = fmaf(v1.y, w[kq * 4 + 1], a1);
            a2 = fmaf(v2.y, w[kq * 4 + 1], a2);
            a3 = fmaf(v3.y, w[kq * 4 + 1], a3);
            a0 = fmaf(v0.z, w[kq * 4 + 2], a0);
            a1 = fmaf(v1.z, w[kq * 4 + 2], a1);
            a2 = fmaf(v2.z, w[kq * 4 + 2], a2);
            a3 = fmaf(v3.z, w[kq * 4 + 2], a3);
            a0 = fmaf(v0.w, w[kq * 4 + 3], a0);
            a1 = fmaf(v1.w, w[kq * 4 + 3], a1);
            a2 = fmaf(v2.w, w[kq * 4 + 3], a2);
            a3 = fmaf(v3.w, w[kq * 4 + 3], a3);
        }
        size_t base = (size_t)(g * 4) * D + lane;
        if (mat) {
            yN[base + 0 * D] = f2bf(a0);
            yN[base + 1 * D] = f2bf(a1);
            yN[base + 2 * D] = f2bf(a2);
            yN[base + 3 * D] = f2bf(a3);
        } else {
            yS[base + 0 * D] = a0;
            yS[base + 1 * D] = a1;
            yS[base + 2 * D] = a2;
            yS[base + 3 * D] = a3;
        }
    }
}

// ---------------- fused mean-aggregate + self + epilogue ----------------
// Single yN array (128 B rows), one UNCONDITIONAL 32-edge round: 8 independent
// uint2 gathers issued back-to-back (MLP=8 for every node; R7 had 4 + a
// branch-serialized 4). Masked slots read row 0 (L1-hit) and contribute *0.0f
// (exact). deg>32 branch is ~3e-5 of waves. Per-accumulator summation order
// identical to R7 -> same absmax. q=lane>>4 picks edge slot, fq=lane&15 picks
// the uint2 (4 bf16) within the 128 B row.
__global__ __launch_bounds__(256) void k_aggf(const char* __restrict__ yN,
        const float* __restrict__ yS,
        const int* __restrict__ cnt, const int* __restrict__ csr,
        float* __restrict__ out, int relu) {
    int node = __builtin_amdgcn_readfirstlane((blockIdx.x * blockDim.x + threadIdx.x) >> 6);
    int lane = threadIdx.x & 63;
    if (node >= N_NODES) return;
    int q = lane >> 4;          // edge sub-slot 0..3
    int fq = lane & 15;         // uint2 slot within the 128 B row
    int deg = cnt[node];
    const int* bucket = csr + (node << 6);
    unsigned foff = (unsigned)fq * 8u;

    float s0 = 0.f, s1 = 0.f, s2 = 0.f, s3 = 0.f;

#define ROUND32(E0)                                                         \
    {                                                                       \
        int i0 = (E0) + q;                                                  \
        int b0 = bucket[i0],      b1 = bucket[i0 + 4];                      \
        int b2 = bucket[i0 + 8],  b3 = bucket[i0 + 12];                     \
        int b4 = bucket[i0 + 16], b5 = bucket[i0 + 20];                     \
        int b6 = bucket[i0 + 24], b7 = bucket[i0 + 28];                     \
        unsigned a0 = (i0      < deg) ? ((unsigned)b0 << 7) : 0u;           \
        unsigned a1 = (i0 + 4  < deg) ? ((unsigned)b1 << 7) : 0u;           \
        unsigned a2 = (i0 + 8  < deg) ? ((unsigned)b2 << 7) : 0u;           \
        unsigned a3 = (i0 + 12 < deg) ? ((unsigned)b3 << 7) : 0u;           \
        unsigned a4 = (i0 + 16 < deg) ? ((unsigned)b4 << 7) : 0u;           \
        unsigned a5 = (i0 + 20 < deg) ? ((unsigned)b5 << 7) : 0u;           \
        unsigned a6 = (i0 + 24 < deg) ? ((unsigned)b6 << 7) : 0u;           \
        unsigned a7 = (i0 + 28 < deg) ? ((unsigned)b7 << 7) : 0u;           \
        float m0 = (i0      < deg) ? 1.f : 0.f;                             \
        float m1 = (i0 + 4  < deg) ? 1.f : 0.f;                             \
        float m2 = (i0 + 8  < deg) ? 1.f : 0.f;                             \
        float m3 = (i0 + 12 < deg) ? 1.f : 0.f;                             \
        float m4 = (i0 + 16 < deg) ? 1.f : 0.f;                             \
        float m5 = (i0 + 20 < deg) ? 1.f : 0.f;                             \
        float m6 = (i0 + 24 < deg) ? 1.f : 0.f;                             \
        float m7 = (i0 + 28 < deg) ? 1.f : 0.f;                             \
        uint2 u0 = *(const uint2*)(yN + a0 + foff);                         \
        uint2 u1 = *(const uint2*)(yN + a1 + foff);                         \
        uint2 u2 = *(const uint2*)(yN + a2 + foff);                         \
        uint2 u3 = *(const uint2*)(yN + a3 + foff);                         \
        uint2 u4 = *(const uint2*)(yN + a4 + foff);                         \
        uint2 u5 = *(const uint2*)(yN + a5 + foff);                         \
        uint2 u6 = *(const uint2*)(yN + a6 + foff);                         \
        uint2 u7 = *(const uint2*)(yN + a7 + foff);                         \
        s0 = fmaf(m0, bflo(u0.x), s0); s0 = fmaf(m1, bflo(u1.x), s0);       \
        s0 = fmaf(m2, bflo(u2.x), s0); s0 = fmaf(m3, bflo(u3.x), s0);       \
        s0 = fmaf(m4, bflo(u4.x), s0); s0 = fmaf(m5, bflo(u5.x), s0);       \
        s0 = fmaf(m6, bflo(u6.x), s0); s0 = fmaf(m7, bflo(u7.x), s0);       \
        s1 = fmaf(m0, bfhi(u0.x), s1); s1 = fmaf(m1, bfhi(u1.x), s1);       \
        s1 = fmaf(m2, bfhi(u2.x), s1); s1 = fmaf(m3, bfhi(u3.x), s1);       \
        s1 = fmaf(m4, bfhi(u4.x), s1); s1 = fmaf(m5, bfhi(u5.x), s1);       \
        s1 = fmaf(m6, bfhi(u6.x), s1); s1 = fmaf(m7, bfhi(u7.x), s1);       \
        s2 = fmaf(m0, bflo(u0.y), s2); s2 = fmaf(m1, bflo(u1.y), s2);       \
        s2 = fmaf(m2, bflo(u2.y), s2); s2 = fmaf(m3, bflo(u3.y), s2);       \
        s2 = fmaf(m4, bflo(u4.y), s2); s2 = fmaf(m5, bflo(u5.y), s2);       \
        s2 = fmaf(m6, bflo(u6.y), s2); s2 = fmaf(m7, bflo(u7.y), s2);       \
        s3 = fmaf(m0, bfhi(u0.y), s3); s3 = fmaf(m1, bfhi(u1.y), s3);       \
        s3 = fmaf(m2, bfhi(u2.y), s3); s3 = fmaf(m3, bfhi(u3.y), s3);       \
        s3 = fmaf(m4, bfhi(u4.y), s3); s3 = fmaf(m5, bfhi(u5.y), s3);       \
        s3 = fmaf(m6, bfhi(u6.y), s3); s3 = fmaf(m7, bfhi(u7.y), s3);       \
    }

    ROUND32(0)
    if (deg > 32) ROUND32(32)      // scalar branch, ~3e-5 of waves
#undef ROUND32

    // merge the 4 edge-slots (xor over the two q bits: 16, 32)
    s0 += __shfl_xor(s0, 16, 64);  s0 += __shfl_xor(s0, 32, 64);
    s1 += __shfl_xor(s1, 16, 64);  s1 += __shfl_xor(s1, 32, 64);
    s2 += __shfl_xor(s2, 16, 64);  s2 += __shfl_xor(s2, 32, 64);
    s3 += __shfl_xor(s3, 16, 64);  s3 += __shfl_xor(s3, 32, 64);

    float sv = (q == 0) ? s0 : (q == 1) ? s1 : (q == 2) ? s2 : s3;
    int f = fq * 4 + q;                      // feature this lane writes
    float self = yS[(size_t)node * D + f];
    float inv = 1.0f / fmaxf((float)deg, 1.0f);
    float acc = self + sv * inv;
    if (relu) acc = fmaxf(acc, 0.f);
    out[(size_t)node * D + f] = acc;
}

extern "C" void kernel_launch(void* const* d_in, const int* in_sizes, int n_in,
                              void* d_out, int out_size, void* d_ws, size_t ws_size,
                              hipStream_t stream) {
    const float* x   = (const float*)d_in[0];
    const int*   src = (const int*)d_in[1];
    const int*   dst = (const int*)d_in[2];
    const float* Ws0 = (const float*)d_in[3];
    const float* Wn0 = (const float*)d_in[4];
    const float* b0  = (const float*)d_in[5];
    const float* Ws1 = (const float*)d_in[6];
    const float* Wn1 = (const float*)d_in[7];
    const float* b1  = (const float*)d_in[8];
    float* out = (float*)d_out;

    // workspace layout
    char* p = (char*)d_ws;
    float*          yS  = (float*)p;          p += (size_t)N_NODES * D * sizeof(float);
    unsigned short* yN  = (unsigned short*)p; p += (size_t)N_NODES * D * sizeof(unsigned short);
    int* cnt = (int*)p;                       p += (size_t)N_NODES * sizeof(int);
    int* csr = (int*)p;                       p += (size_t)N_NODES * BCAP * sizeof(int);

    const int aggBlocks = (N_NODES + 3) / 4;     // wave per node, 4 per block

    // layer 0 transform also zeroes cnt (replaces a memset dispatch);
    // k_fill2 is stream-ordered after it, so the zero is visible.
    k_xform<<<1024, 256, 0, stream>>>(x, Ws0, Wn0, b0, yS, yN, cnt, 1);
    k_fill2<<<1024, 256, 0, stream>>>(src, dst, cnt, csr);
    k_aggf<<<aggBlocks, 256, 0, stream>>>((const char*)yN, yS, cnt, csr, out, 1);

    // layer 1
    k_xform<<<1024, 256, 0, stream>>>(out, Ws1, Wn1, b1, yS, yN, cnt, 0);
    k_aggf<<<aggBlocks, 256, 0, stream>>>((const char*)yN, yS, cnt, csr, out, 0);
}

// Round 10
// 197.499 us; speedup vs baseline: 1.0682x; 1.0090x over previous
//
#include <hip/hip_runtime.h>

#define N_NODES 50000
#define N_EDGES 800000
#define D 64
#define NSLICE 8
#define SLICE_N ((N_NODES + NSLICE - 1) / NSLICE)   // 6250
#define BCAP 64        // bucket capacity; deg ~ Poisson(16), P(deg>=64) ~ 1e-19

// float -> bf16 (round-to-nearest-even), as raw ushort
__device__ __forceinline__ unsigned short f2bf(float f) {
    unsigned int u = __builtin_bit_cast(unsigned int, f);
    u += 0x7fffu + ((u >> 16) & 1u);
    return (unsigned short)(u >> 16);
}
// unpack a uint holding two bf16 (little-endian: low ushort = even feature)
__device__ __forceinline__ float bflo(unsigned int u) {
    return __builtin_bit_cast(float, u << 16);
}
__device__ __forceinline__ float bfhi(unsigned int u) {
    return __builtin_bit_cast(float, u & 0xffff0000u);
}

// ---------------- bucketed CSR fill (XCD-partitioned by dst slice) ----------------
// Node i owns csr[i*64 .. i*64+63]; cnt[i] is the atomic cursor and doubles as
// the degree. Slice partition (blockIdx&7) keeps each bucket line dirty in one
// XCD's L2 (R2 showed 17x write amplification without it). cnt is zeroed by
// the preceding k_xform dispatch (stream-ordered).
__global__ __launch_bounds__(256) void k_fill2(const int* __restrict__ src,
                                               const int* __restrict__ dst,
                                               int* __restrict__ cnt,
                                               int* __restrict__ csr) {
    int slice = blockIdx.x & (NSLICE - 1);
    int lo = slice * SLICE_N, hi = lo + SLICE_N;
    int gblk = blockIdx.x >> 3, nblk = gridDim.x >> 3;
    for (int e = gblk * blockDim.x + threadIdx.x; e < N_EDGES; e += nblk * blockDim.x) {
        int d = dst[e];
        if (d >= lo && d < hi) {
            int p = atomicAdd(&cnt[d], 1);
            csr[(d << 6) + p] = src[e];
        }
    }
}

// ---------------- transform: yS = h@Ws + b (fp32), yN = h@Wn (bf16) ----------------
// Wave-specialized (even waves -> Ws/yS, odd -> Wn/yN). Lane = output column,
// W column held in 64 VGPRs; h rows read as wave-uniform float4.
// zero_cnt=1 (layer 0 only): first 196 blocks also zero cnt[] — replaces the
// hipMemsetAsync dispatch.
__global__ __launch_bounds__(256, 4) void k_xform(const float* __restrict__ h,
        const float* __restrict__ Ws, const float* __restrict__ Wn,
        const float* __restrict__ b,
        float* __restrict__ yS, unsigned short* __restrict__ yN,
        int* __restrict__ cnt, int zero_cnt) {
    if (zero_cnt && blockIdx.x < 196) {
        int i = blockIdx.x * 256 + threadIdx.x;
        if (i < N_NODES) cnt[i] = 0;
    }
    int lane = threadIdx.x & 63;
    int gwave = __builtin_amdgcn_readfirstlane((blockIdx.x * blockDim.x + threadIdx.x) >> 6);
    int nwaves = (gridDim.x * blockDim.x) >> 6;

    int mat = gwave & 1;
    const float* W = mat ? Wn : Ws;

    float w[D];
#pragma unroll
    for (int k = 0; k < D; ++k) w[k] = W[k * D + lane];
    float bj = mat ? 0.f : b[lane];

    const int ngroups = (N_NODES + 3) / 4;   // 12500, exact
    for (int g = gwave >> 1; g < ngroups; g += (nwaves >> 1)) {
        const float* x0 = h + (size_t)(g * 4) * D;
        float a0 = bj, a1 = bj, a2 = bj, a3 = bj;
#pragma unroll
        for (int kq = 0; kq < 16; ++kq) {
            float4 v0 = *(const float4*)(x0 + 0 * D + kq * 4);
            float4 v1 = *(const float4*)(x0 + 1 * D + kq * 4);
            float4 v2 = *(const float4*)(x0 + 2 * D + kq * 4);
            float4 v3 = *(const float4*)(x0 + 3 * D + kq * 4);
            a0 = fmaf(v0.x, w[kq * 4 + 0], a0);
            a1 = fmaf(v1.x, w[kq * 4 + 0], a1);
            a2 = fmaf(v2.x, w[kq * 4 + 0], a2);
            a3 = fmaf(v3.x, w[kq * 4 + 0], a3);
            a0 = fmaf(v0.y, w[kq * 4 + 1], a0);
            a1 = fmaf(v1.y, w[kq * 4 + 1], a1);
            a2 = fmaf(v2.y, w[kq * 4 + 1], a2);
            a3 = fmaf(v3.y, w[kq * 4 + 1], a3);
            a0 = fmaf(v0.z, w[kq * 4 + 2], a0);
            a1 = fmaf(v1.z, w[kq * 4 + 2], a1);
            a2 = fmaf(v2.z, w[kq * 4 + 2], a2);
            a3 = fmaf(v3.z, w[kq * 4 + 2], a3);
            a0 = fmaf(v0.w, w[kq * 4 + 3], a0);
            a1 = fmaf(v1.w, w[kq * 4 + 3], a1);
            a2 = fmaf(v2.w, w[kq * 4 + 3], a2);
            a3 = fmaf(v3.w, w[kq * 4 + 3], a3);
        }
        size_t base = (size_t)(g * 4) * D + lane;
        if (mat) {
            yN[base + 0 * D] = f2bf(a0);
            yN[base + 1 * D] = f2bf(a1);
            yN[base + 2 * D] = f2bf(a2);
            yN[base + 3 * D] = f2bf(a3);
        } else {
            yS[base + 0 * D] = a0;
            yS[base + 1 * D] = a1;
            yS[base + 2 * D] = a2;
            yS[base + 3 * D] = a3;
        }
    }
}

// ---------------- fused mean-aggregate + self + epilogue (v3) ----------------
// uint4 gathers: 16 B/lane x 64 lanes = 1 KB per instruction (8 rows x 128 B).
// q=lane>>3 picks 1 of 8 edges, fq=lane&7 picks the 16 B chunk of the row.
// A 16-edge round = 2 bucket loads + 2 gathers (vs 4+4 uint2 in R7, 8+8 in R9
// — R9's A/B showed aggf is VMEM-instruction-throughput-bound, so halve the
// instruction count per edge and keep rounds deg-adaptive to avoid masked
// waste). Masked slots read row 0 (L1-hit) and contribute *0.0f (exact).
// Epilogue: 8 accumulators, 3 xor-shuffles each, lane (q,fq) -> feature fq*8+q.
__global__ __launch_bounds__(256) void k_aggf(const char* __restrict__ yN,
        const float* __restrict__ yS,
        const int* __restrict__ cnt, const int* __restrict__ csr,
        float* __restrict__ out, int relu) {
    int node = __builtin_amdgcn_readfirstlane((blockIdx.x * blockDim.x + threadIdx.x) >> 6);
    int lane = threadIdx.x & 63;
    int q = lane >> 3;          // edge sub-slot 0..7
    int fq = lane & 7;          // uint4 slot within the 128 B row
    int deg = cnt[node];
    const int* bucket = csr + (node << 6);
    unsigned foff = (unsigned)fq * 16u;

    float s0 = 0.f, s1 = 0.f, s2 = 0.f, s3 = 0.f;
    float s4 = 0.f, s5 = 0.f, s6 = 0.f, s7 = 0.f;

#define ROUND16(E0)                                                         \
    {                                                                       \
        int i0 = (E0) + q, i1 = i0 + 8;                                     \
        int b0 = bucket[i0], b1 = bucket[i1];                               \
        unsigned a0 = (i0 < deg) ? ((unsigned)b0 << 7) : 0u;                \
        unsigned a1 = (i1 < deg) ? ((unsigned)b1 << 7) : 0u;                \
        float m0 = (i0 < deg) ? 1.f : 0.f;                                  \
        float m1 = (i1 < deg) ? 1.f : 0.f;                                  \
        uint4 u0 = *(const uint4*)(yN + a0 + foff);                         \
        uint4 u1 = *(const uint4*)(yN + a1 + foff);                         \
        s0 = fmaf(m0, bflo(u0.x), s0); s0 = fmaf(m1, bflo(u1.x), s0);       \
        s1 = fmaf(m0, bfhi(u0.x), s1); s1 = fmaf(m1, bfhi(u1.x), s1);       \
        s2 = fmaf(m0, bflo(u0.y), s2); s2 = fmaf(m1, bflo(u1.y), s2);       \
        s3 = fmaf(m0, bfhi(u0.y), s3); s3 = fmaf(m1, bfhi(u1.y), s3);       \
        s4 = fmaf(m0, bflo(u0.z), s4); s4 = fmaf(m1, bflo(u1.z), s4);       \
        s5 = fmaf(m0, bfhi(u0.z), s5); s5 = fmaf(m1, bfhi(u1.z), s5);       \
        s6 = fmaf(m0, bflo(u0.w), s6); s6 = fmaf(m1, bflo(u1.w), s6);       \
        s7 = fmaf(m0, bfhi(u0.w), s7); s7 = fmaf(m1, bfhi(u1.w), s7);       \
    }

    ROUND16(0)                          // deg<=16: 53% of nodes stop here
    if (deg > 16) ROUND16(16)           // ~44%
    if (deg > 32) {                     // ~3%
        ROUND16(32)
        if (deg > 48) ROUND16(48)       // ~1e-4
    }
#undef ROUND16

    // merge the 8 edge-slots (xor over the three q bits: 8, 16, 32)
    s0 += __shfl_xor(s0, 8, 64); s0 += __shfl_xor(s0, 16, 64); s0 += __shfl_xor(s0, 32, 64);
    s1 += __shfl_xor(s1, 8, 64); s1 += __shfl_xor(s1, 16, 64); s1 += __shfl_xor(s1, 32, 64);
    s2 += __shfl_xor(s2, 8, 64); s2 += __shfl_xor(s2, 16, 64); s2 += __shfl_xor(s2, 32, 64);
    s3 += __shfl_xor(s3, 8, 64); s3 += __shfl_xor(s3, 16, 64); s3 += __shfl_xor(s3, 32, 64);
    s4 += __shfl_xor(s4, 8, 64); s4 += __shfl_xor(s4, 16, 64); s4 += __shfl_xor(s4, 32, 64);
    s5 += __shfl_xor(s5, 8, 64); s5 += __shfl_xor(s5, 16, 64); s5 += __shfl_xor(s5, 32, 64);
    s6 += __shfl_xor(s6, 8, 64); s6 += __shfl_xor(s6, 16, 64); s6 += __shfl_xor(s6, 32, 64);
    s7 += __shfl_xor(s7, 8, 64); s7 += __shfl_xor(s7, 16, 64); s7 += __shfl_xor(s7, 32, 64);

    float sv = (q == 0) ? s0 : (q == 1) ? s1 : (q == 2) ? s2 : (q == 3) ? s3
             : (q == 4) ? s4 : (q == 5) ? s5 : (q == 6) ? s6 : s7;
    int f = fq * 8 + q;                      // feature this lane writes
    float self = yS[(size_t)node * D + f];
    float inv = 1.0f / fmaxf((float)deg, 1.0f);
    float acc = self + sv * inv;
    if (relu) acc = fmaxf(acc, 0.f);
    out[(size_t)node * D + f] = acc;
}

extern "C" void kernel_launch(void* const* d_in, const int* in_sizes, int n_in,
                              void* d_out, int out_size, void* d_ws, size_t ws_size,
                              hipStream_t stream) {
    const float* x   = (const float*)d_in[0];
    const int*   src = (const int*)d_in[1];
    const int*   dst = (const int*)d_in[2];
    const float* Ws0 = (const float*)d_in[3];
    const float* Wn0 = (const float*)d_in[4];
    const float* b0  = (const float*)d_in[5];
    const float* Ws1 = (const float*)d_in[6];
    const float* Wn1 = (const float*)d_in[7];
    const float* b1  = (const float*)d_in[8];
    float* out = (float*)d_out;

    // workspace layout
    char* p = (char*)d_ws;
    float*          yS  = (float*)p;          p += (size_t)N_NODES * D * sizeof(float);
    unsigned short* yN  = (unsigned short*)p; p += (size_t)N_NODES * D * sizeof(unsigned short);
    int* cnt = (int*)p;                       p += (size_t)N_NODES * sizeof(int);
    int* csr = (int*)p;                       p += (size_t)N_NODES * BCAP * sizeof(int);

    const int aggBlocks = (N_NODES + 3) / 4;     // wave per node, 4 per block, exact

    // layer 0 transform also zeroes cnt (replaces a memset dispatch);
    // k_fill2 is stream-ordered after it, so the zero is visible.
    k_xform<<<1024, 256, 0, stream>>>(x, Ws0, Wn0, b0, yS, yN, cnt, 1);
    k_fill2<<<1024, 256, 0, stream>>>(src, dst, cnt, csr);
    k_aggf<<<aggBlocks, 256, 0, stream>>>((const char*)yN, yS, cnt, csr, out, 1);

    // layer 1
    k_xform<<<1024, 256, 0, stream>>>(out, Ws1, Wn1, b1, yS, yN, cnt, 0);
    k_aggf<<<aggBlocks, 256, 0, stream>>>((const char*)yN, yS, cnt, csr, out, 0);
}